// Round 1
// baseline (3565.055 us; speedup 1.0000x reference)
//
#include <hip/hip_runtime.h>
#include <hip/hip_bf16.h>
#include <math.h>

#define B_ 256
#define L_ 512
#define V_ 256
#define E_ 256
#define H_ 1024

typedef float  f32x4  __attribute__((ext_vector_type(4)));
typedef short  bf16x8 __attribute__((ext_vector_type(8)));

static __device__ __forceinline__ ushort f2bf(float v) {
    __hip_bfloat16 b = __float2bfloat16(v);
    return *reinterpret_cast<ushort*>(&b);
}

static __device__ __forceinline__ void load_lds16(const void* g, void* l) {
    __builtin_amdgcn_global_load_lds(
        (const __attribute__((address_space(1))) void*)(g),
        (__attribute__((address_space(3))) void*)(l), 16, 0, 0);
}

// ---------- prep: transpose f32 [R][C] -> bf16 [C][R] ----------
__global__ void k_transpose_bf16(const float* __restrict__ in, ushort* __restrict__ out,
                                 int R, int C) {
    __shared__ float tile[64][65];
    int bx = blockIdx.x;           // over C/64
    int by = blockIdx.y;           // over R/64
    int tid = threadIdx.x;
    int g = tid >> 6, l = tid & 63;
    for (int i = 0; i < 16; ++i) {
        int r = g * 16 + i;
        tile[r][l] = in[(size_t)(by * 64 + r) * C + bx * 64 + l];
    }
    __syncthreads();
    for (int i = 0; i < 16; ++i) {
        int c = g * 16 + i;
        out[(size_t)(bx * 64 + c) * R + by * 64 + l] = f2bf(tile[l][c]);
    }
}

// ---------- prep: f32 -> bf16 copy ----------
__global__ void k_f32_to_bf16(const float* __restrict__ in, ushort* __restrict__ out, int n) {
    int i = blockIdx.x * blockDim.x + threadIdx.x;
    if (i < n) out[i] = f2bf(in[i]);
}

// ---------- prep: proj[t][h] = sum_e emb[t][e] * W_e[e][h]  (f32) ----------
__global__ void k_proj(const float* __restrict__ emb, const float* __restrict__ We,
                       float* __restrict__ proj) {
    __shared__ float er[E_];
    int t = blockIdx.x;
    int h = blockIdx.y * 256 + threadIdx.x;
    er[threadIdx.x] = emb[t * E_ + threadIdx.x];   // blockDim.x == 256 == E_
    __syncthreads();
    float acc = 0.f;
#pragma unroll 8
    for (int e = 0; e < E_; ++e) acc += er[e] * We[(size_t)e * H_ + h];
    proj[(size_t)t * H_ + h] = acc;
}

// ---------- per-step kernel ----------
// A-phase: h_t[r0..r0+32][c0..c0+32] = tanh(proj[x[b][t]][c] + h_{t-1} @ W_h)
// B-phase (t>0): logits[:, t-1, :] tile [16 x 16] from the staged h_{t-1} panel.
__global__ __launch_bounds__(256, 1) void k_step(
    const int* __restrict__ x, const float* __restrict__ proj,
    const ushort* __restrict__ WhT, const ushort* __restrict__ WoT,
    const ushort* __restrict__ hprev, ushort* __restrict__ hnext,
    float* __restrict__ logits, float* __restrict__ final_h, int t)
{
    __shared__ ushort lds_h[32 * 1024];   // h_{t-1} rows r0..r0+32, swizzled (64KB)
    __shared__ ushort lds_w[32 * 1024];   // WhT rows c0..c0+32, swizzled (64KB)
    __shared__ float  red[4 * 64 * 4];    // B-phase cross-wave reduce (4KB)

    int tid = threadIdx.x;
    int w = tid >> 6, lane = tid & 63;
    int l15 = lane & 15, l4 = lane >> 4;
    int bid = blockIdx.x;
    int rg = bid >> 5;            // 0..7  -> rows rg*32
    int cg = bid & 31;            // 0..31 -> cols cg*32
    int r0 = rg * 32, c0 = cg * 32;

    // --- stage both panels, 64KB each, LDS(row,b) = src(row, b ^ ((row&7)<<4))
    {
        const char* hsrc = (const char*)(hprev + (size_t)r0 * H_);
        const char* wsrc = (const char*)(WhT + (size_t)c0 * H_);
        char* hd = (char*)lds_h;
        char* wd = (char*)lds_w;
        for (int i = 0; i < 16; ++i) {
            int chunk = (w * 16 + i) * 1024;       // wave-uniform LDS base
            int o = chunk + lane * 16;             // this lane's LDS byte offset
            int row = o >> 11, b = o & 2047;
            int so = row * 2048 + (b ^ ((row & 7) << 4));
            load_lds16(hsrc + so, hd + chunk);
            load_lds16(wsrc + so, wd + chunk);
        }
    }
    asm volatile("s_waitcnt vmcnt(0)" ::: "memory");
    __syncthreads();

    // --- A phase: each wave computes one 16x16 quadrant of the 32x32 tile
    int a = w >> 1, bc = w & 1;
    f32x4 acc = {0.f, 0.f, 0.f, 0.f};
    {
        int arow = a * 16 + l15;                  // row within staged panel
        int brow = bc * 16 + l15;                 // col (as WhT row) within panel
        const char* ha = (const char*)lds_h + arow * 2048;
        const char* wa = (const char*)lds_w + brow * 2048;
        int as = (arow & 7) << 4, bs = (brow & 7) << 4;
#pragma unroll
        for (int kk = 0; kk < 32; ++kk) {
            int kb = (kk * 32 + l4 * 8) * 2;      // byte offset along k
            bf16x8 af = *(const bf16x8*)(ha + (kb ^ as));
            bf16x8 bf = *(const bf16x8*)(wa + (kb ^ bs));
            acc = __builtin_amdgcn_mfma_f32_16x16x32_bf16(af, bf, acc, 0, 0, 0);
        }
    }
    {
        int gcol = c0 + bc * 16 + l15;
#pragma unroll
        for (int j = 0; j < 4; ++j) {
            int grow = r0 + a * 16 + l4 * 4 + j;
            int xv = x[grow * L_ + t];
            float z = acc[j] + proj[(size_t)xv * H_ + gcol];
            float hv = tanhf(z);
            hnext[(size_t)grow * H_ + gcol] = f2bf(hv);
            if (t == L_ - 1) final_h[(size_t)grow * H_ + gcol] = hv;
        }
    }

    // --- B phase: logits[:, t-1, :]; block covers rows rg*32+(cg>>4)*16..+16,
    // vocab cols (cg&15)*16..+16; waves split K=1024 four ways.
    if (t > 0) {
        int lrg = cg >> 4;                         // 0/1 within the staged 32 rows
        int vcol0 = (cg & 15) * 16;
        int srow = lrg * 16 + l15;
        const char* ha = (const char*)lds_h + srow * 2048;
        int as = (srow & 7) << 4;
        const ushort* wo = WoT + (size_t)(vcol0 + l15) * H_;
        f32x4 lacc = {0.f, 0.f, 0.f, 0.f};
#pragma unroll
        for (int kk = 0; kk < 8; ++kk) {
            int k = w * 256 + kk * 32 + l4 * 8;
            bf16x8 af = *(const bf16x8*)(ha + ((2 * k) ^ as));
            bf16x8 bf = *(const bf16x8*)(wo + k);
            lacc = __builtin_amdgcn_mfma_f32_16x16x32_bf16(af, bf, lacc, 0, 0, 0);
        }
#pragma unroll
        for (int j = 0; j < 4; ++j) red[(w * 64 + lane) * 4 + j] = lacc[j];
        __syncthreads();
        if (w == 0) {
            int growb = rg * 32 + lrg * 16 + l4 * 4;
#pragma unroll
            for (int j = 0; j < 4; ++j) {
                float s = red[(0 * 64 + lane) * 4 + j] + red[(1 * 64 + lane) * 4 + j]
                        + red[(2 * 64 + lane) * 4 + j] + red[(3 * 64 + lane) * 4 + j];
                logits[((size_t)(growb + j) * L_ + (t - 1)) * V_ + vcol0 + l15] = s;
            }
        }
    }
}

// ---------- epilogue: logits[:, L-1, :] from h_{L-1} ----------
__global__ __launch_bounds__(256, 1) void k_logits_last(
    const ushort* __restrict__ hlast, const ushort* __restrict__ WoT,
    float* __restrict__ logits)
{
    __shared__ float red[4 * 64 * 4];
    int tid = threadIdx.x, w = tid >> 6, lane = tid & 63;
    int l15 = lane & 15, l4 = lane >> 4;
    int bid = blockIdx.x;
    int lrow0 = (bid >> 4) * 16, vcol0 = (bid & 15) * 16;
    const ushort* ha = hlast + (size_t)(lrow0 + l15) * H_;
    const ushort* wo = WoT + (size_t)(vcol0 + l15) * H_;
    f32x4 lacc = {0.f, 0.f, 0.f, 0.f};
#pragma unroll
    for (int kk = 0; kk < 8; ++kk) {
        int k = w * 256 + kk * 32 + l4 * 8;
        bf16x8 af = *(const bf16x8*)(ha + k);
        bf16x8 bf = *(const bf16x8*)(wo + k);
        lacc = __builtin_amdgcn_mfma_f32_16x16x32_bf16(af, bf, lacc, 0, 0, 0);
    }
#pragma unroll
    for (int j = 0; j < 4; ++j) red[(w * 64 + lane) * 4 + j] = lacc[j];
    __syncthreads();
    if (w == 0) {
#pragma unroll
        for (int j = 0; j < 4; ++j) {
            float s = red[(0 * 64 + lane) * 4 + j] + red[(1 * 64 + lane) * 4 + j]
                    + red[(2 * 64 + lane) * 4 + j] + red[(3 * 64 + lane) * 4 + j];
            logits[((size_t)(lrow0 + l4 * 4 + j) * L_ + (L_ - 1)) * V_ + vcol0 + l15] = s;
        }
    }
}

extern "C" void kernel_launch(void* const* d_in, const int* in_sizes, int n_in,
                              void* d_out, int out_size, void* d_ws, size_t ws_size,
                              hipStream_t stream)
{
    const int*   x   = (const int*)d_in[0];
    const float* hid = (const float*)d_in[1];
    const float* emb = (const float*)d_in[2];
    const float* We  = (const float*)d_in[3];
    const float* Wh  = (const float*)d_in[4];
    const float* Wo  = (const float*)d_in[5];

    float* logits  = (float*)d_out;                       // [B][L][V] f32
    float* final_h = logits + (size_t)B_ * L_ * V_;       // [B][H] f32

    char* ws = (char*)d_ws;
    float*  proj = (float*)(ws);                          // 1 MB f32 [V][H]
    ushort* WhT  = (ushort*)(ws + (1u << 20));            // 2 MB bf16 [H][H] (transposed)
    ushort* WoT  = (ushort*)(ws + 3u * (1u << 20));       // 0.5 MB bf16 [V][H] (transposed)
    ushort* hb0  = (ushort*)(ws + 3u * (1u << 20) + (1u << 19));       // 0.5 MB bf16 [B][H]
    ushort* hb1  = (ushort*)(ws + 3u * (1u << 20) + 2u * (1u << 19));  // 0.5 MB bf16 [B][H]

    // prep
    k_transpose_bf16<<<dim3(16, 16), 256, 0, stream>>>(Wh, WhT, H_, H_);
    k_transpose_bf16<<<dim3(4, 16),  256, 0, stream>>>(Wo, WoT, H_, V_);
    k_f32_to_bf16<<<dim3(1024), 256, 0, stream>>>(hid, hb0, B_ * H_);
    k_proj<<<dim3(256, 4), 256, 0, stream>>>(emb, We, proj);

    // sequential scan: h_t into hb[(t+1)&1]; logits for t-1 fused into step t
    for (int t = 0; t < L_; ++t) {
        const ushort* hp = (t & 1) ? hb1 : hb0;
        ushort*       hn = (t & 1) ? hb0 : hb1;
        k_step<<<dim3(256), 256, 0, stream>>>(x, proj, WhT, WoT, hp, hn,
                                              logits, final_h, t);
    }
    // h_{511} lives in hb0 (t=511 odd -> hn = hb0)
    k_logits_last<<<dim3(256), 256, 0, stream>>>(hb0, WoT, logits);
}